// Round 1
// baseline (286.216 us; speedup 1.0000x reference)
//
#include <hip/hip_runtime.h>
#include <math.h>

// src [B=16,S=4096,DM=768] fp32, mask [B,S] bool, query [H=8,D=96] fp32,
// out [B,768] fp32. Single-pass weighted pooling:
//   w_s = exp(q.k_s)  (no max-subtraction: scores ~ N(0,1), fp32-safe)
//   out = sum_s w_s * (k_s + pe_s) / sum_s w_s
// PE via sin/cos rotation recurrence (no per-row transcendentals).
//
// v2: DENSE STREAMING. One block = (b, 32 consecutive rows) x ALL 8 heads.
// Each wave reads one full contiguous 3072B row per iteration (24x128B
// consecutive segments); block footprint = 98 KB contiguous. Replaces the
// v1 per-head layout whose loads scattered 8x128B segments across 24 KB
// with 96 KB iteration hops (suspected DRAM-locality killer at 0.73 TB/s).
namespace {
constexpr int kB = 16;
constexpr int kS = 4096;
constexpr int kH = 8;
constexpr int kD = 96;
constexpr int kDM = 768;
constexpr int kNChunk = 128;            // 16*128 = 2048 blocks
constexpr int kCS = kS / kNChunk;       // 32 rows per chunk
constexpr int kRPI = 4;                 // rows per block-iteration (1/wave)
constexpr int kIters = kCS / kRPI;      // 8
constexpr float kPeScale = 0.03608439182435161f;        // 768^-0.5
constexpr float kNegLog = -9.210340371976184f / 768.0f; // -ln(1e4)/768
}

// 256 threads: j = t&7 -> 3 float4 of a 96-dim head slice; h = (t>>3)&7;
// rs = t>>6 -> wave == row slot. Each thread accumulates sum_w and
// sum_w*(x+pe) over its 8 rows; LDS merge across the 4 waves at the end.
__global__ __launch_bounds__(256)
void attn_partial_kernel(const float* __restrict__ src,
                         const unsigned char* __restrict__ mask,
                         const float* __restrict__ query,
                         float* __restrict__ wsO,
                         float* __restrict__ wsL)
{
    const int blk = blockIdx.x;
    const int chunk = blk % kNChunk;
    const int b = blk / kNChunk;
    const int t = (int)threadIdx.x;
    const int j = t & 7;
    const int h = (t >> 3) & 7;
    const int rs = t >> 6;              // wave id == row slot
    const int lane = t & 63;

    const float* qh = query + h * kD + 4 * j;
    const float4 q0 = *(const float4*)(qh);
    const float4 q1 = *(const float4*)(qh + 32);
    const float4 q2 = *(const float4*)(qh + 64);

    // Frequencies for this thread's 6 (sin,cos) channel pairs.
    const int cbase = h * kD + 4 * j;
    const float f0 = __expf(kNegLog * (float)(cbase));
    const float f1 = __expf(kNegLog * (float)(cbase + 2));
    const float f2 = __expf(kNegLog * (float)(cbase + 32));
    const float f3 = __expf(kNegLog * (float)(cbase + 34));
    const float f4 = __expf(kNegLog * (float)(cbase + 64));
    const float f5 = __expf(kNegLog * (float)(cbase + 66));

    // Initial phase at s0 = chunk*kCS + rs; rotation step for ds = kRPI rows.
    const float s0f = (float)(chunk * kCS + rs);
    float sn0, cs0, sn1, cs1, sn2, cs2, sn3, cs3, sn4, cs4, sn5, cs5;
    __sincosf(s0f * f0, &sn0, &cs0);
    __sincosf(s0f * f1, &sn1, &cs1);
    __sincosf(s0f * f2, &sn2, &cs2);
    __sincosf(s0f * f3, &sn3, &cs3);
    __sincosf(s0f * f4, &sn4, &cs4);
    __sincosf(s0f * f5, &sn5, &cs5);
    float dsn0, dcs0, dsn1, dcs1, dsn2, dcs2, dsn3, dcs3, dsn4, dcs4, dsn5, dcs5;
    __sincosf((float)kRPI * f0, &dsn0, &dcs0);
    __sincosf((float)kRPI * f1, &dsn1, &dcs1);
    __sincosf((float)kRPI * f2, &dsn2, &dcs2);
    __sincosf((float)kRPI * f3, &dsn3, &dcs3);
    __sincosf((float)kRPI * f4, &dsn4, &dcs4);
    __sincosf((float)kRPI * f5, &dsn5, &dcs5);

    float l = 0.0f;
    float o[12];
#pragma unroll
    for (int k = 0; k < 12; ++k) o[k] = 0.0f;

    const float* baseT = src + ((size_t)b * kS + (size_t)(chunk * kCS + rs)) * kDM
                       + h * kD + 4 * j;
    const unsigned char* mbase = mask + (size_t)b * kS + chunk * kCS + rs;

    // software pipeline: loads for iteration it+1 issued before compute of it
    float4 x0 = *(const float4*)(baseT);
    float4 x1 = *(const float4*)(baseT + 32);
    float4 x2 = *(const float4*)(baseT + 64);
    unsigned char mk = mbase[0];

#pragma unroll
    for (int it = 0; it < kIters; ++it) {
        float4 nx0 = {}, nx1 = {}, nx2 = {};
        unsigned char nmk = 0;
        if (it + 1 < kIters) {
            const float* np = baseT + (size_t)(it + 1) * kRPI * kDM;
            nx0 = *(const float4*)(np);
            nx1 = *(const float4*)(np + 32);
            nx2 = *(const float4*)(np + 64);
            nmk = mbase[(it + 1) * kRPI];
        }

        // score = q . key (partial dot, reduce across the 8 lanes of group h)
        float pd = x0.x * q0.x + x0.y * q0.y + x0.z * q0.z + x0.w * q0.w
                 + x1.x * q1.x + x1.y * q1.y + x1.z * q1.z + x1.w * q1.w
                 + x2.x * q2.x + x2.y * q2.y + x2.z * q2.z + x2.w * q2.w;
        pd += __shfl_xor(pd, 1, 8);
        pd += __shfl_xor(pd, 2, 8);
        pd += __shfl_xor(pd, 4, 8);

        const float w = mk ? 0.0f : __expf(pd);
        l += w;

        o[0]  = fmaf(w, fmaf(sn0, kPeScale, x0.x), o[0]);
        o[1]  = fmaf(w, fmaf(cs0, kPeScale, x0.y), o[1]);
        o[2]  = fmaf(w, fmaf(sn1, kPeScale, x0.z), o[2]);
        o[3]  = fmaf(w, fmaf(cs1, kPeScale, x0.w), o[3]);
        o[4]  = fmaf(w, fmaf(sn2, kPeScale, x1.x), o[4]);
        o[5]  = fmaf(w, fmaf(cs2, kPeScale, x1.y), o[5]);
        o[6]  = fmaf(w, fmaf(sn3, kPeScale, x1.z), o[6]);
        o[7]  = fmaf(w, fmaf(cs3, kPeScale, x1.w), o[7]);
        o[8]  = fmaf(w, fmaf(sn4, kPeScale, x2.x), o[8]);
        o[9]  = fmaf(w, fmaf(cs4, kPeScale, x2.y), o[9]);
        o[10] = fmaf(w, fmaf(sn5, kPeScale, x2.z), o[10]);
        o[11] = fmaf(w, fmaf(cs5, kPeScale, x2.w), o[11]);

        // rotate phases forward by kRPI rows (4 FMA-class ops per pair)
        float tns, tnc;
        tns = fmaf(sn0, dcs0, cs0 * dsn0); tnc = fmaf(cs0, dcs0, -sn0 * dsn0); sn0 = tns; cs0 = tnc;
        tns = fmaf(sn1, dcs1, cs1 * dsn1); tnc = fmaf(cs1, dcs1, -sn1 * dsn1); sn1 = tns; cs1 = tnc;
        tns = fmaf(sn2, dcs2, cs2 * dsn2); tnc = fmaf(cs2, dcs2, -sn2 * dsn2); sn2 = tns; cs2 = tnc;
        tns = fmaf(sn3, dcs3, cs3 * dsn3); tnc = fmaf(cs3, dcs3, -sn3 * dsn3); sn3 = tns; cs3 = tnc;
        tns = fmaf(sn4, dcs4, cs4 * dsn4); tnc = fmaf(cs4, dcs4, -sn4 * dsn4); sn4 = tns; cs4 = tnc;
        tns = fmaf(sn5, dcs5, cs5 * dsn5); tnc = fmaf(cs5, dcs5, -sn5 * dsn5); sn5 = tns; cs5 = tnc;

        x0 = nx0; x1 = nx1; x2 = nx2; mk = nmk;
    }

    // ---- block-level merge across the 4 waves (LDS) ----
    __shared__ float osh[4][64][12];   // 12 KB
    __shared__ float lsh[4][8];

    // every lane holds a distinct (h,j) partial now — no intra-wave O reduce
#pragma unroll
    for (int k = 0; k < 12; ++k) osh[rs][lane][k] = o[k];
    if (j == 0) lsh[rs][h] = l;        // l identical across the 8 j-lanes
    __syncthreads();

    // write O partial: thread t -> (hh = t>>5, dg = t&31), 3 channels each
    const int hh = t >> 5;
    const int dg = t & 31;
    const int jj = dg >> 2;
    const int qq = dg & 3;
    const int ln = hh * 8 + jj;
#pragma unroll
    for (int s = 0; s < 3; ++s) {
        const int d = s * 32 + dg;
        const int k = s * 4 + qq;
        wsO[((size_t)blk * kH + hh) * kD + d] =
            osh[0][ln][k] + osh[1][ln][k] + osh[2][ln][k] + osh[3][ln][k];
    }
    if (t < kH) {
        wsL[(size_t)blk * kH + t] = lsh[0][t] + lsh[1][t] + lsh[2][t] + lsh[3][t];
    }
}

// Merge kNChunk partials per (b,h): out = sum_c O_c / sum_c L_c.
__global__ __launch_bounds__(128)
void attn_combine_kernel(const float* __restrict__ wsO,
                         const float* __restrict__ wsL,
                         float* __restrict__ out)
{
    const int bh = (int)blockIdx.x;    // b*8 + h
    const int b = bh >> 3;
    const int h = bh & 7;
    const int t = (int)threadIdx.x;

    float L = 0.0f;
#pragma unroll 8
    for (int c = 0; c < kNChunk; ++c)
        L += wsL[((size_t)(b * kNChunk + c)) * kH + h];

    if (t < kD) {
        float Od = 0.0f;
#pragma unroll 8
        for (int c = 0; c < kNChunk; ++c)
            Od += wsO[((size_t)(b * kNChunk + c) * kH + h) * kD + t];
        out[(size_t)bh * kD + t] = Od / L;
    }
}

extern "C" void kernel_launch(void* const* d_in, const int* in_sizes, int n_in,
                              void* d_out, int out_size, void* d_ws, size_t ws_size,
                              hipStream_t stream)
{
    const float* src = (const float*)d_in[0];
    const unsigned char* mask = (const unsigned char*)d_in[1];
    const float* query = (const float*)d_in[2];
    float* out = (float*)d_out;

    float* wsO = (float*)d_ws;                                   // [2048*8, 96]
    float* wsL = wsO + (size_t)kB * kNChunk * kH * kD;           // [2048*8]

    hipLaunchKernelGGL(attn_partial_kernel,
                       dim3(kB * kNChunk), dim3(256), 0, stream,
                       src, mask, query, wsO, wsL);
    hipLaunchKernelGGL(attn_combine_kernel,
                       dim3(kB * kH), dim3(128), 0, stream,
                       wsO, wsL, out);
}